// Round 4
// baseline (275.512 us; speedup 1.0000x reference)
//
#include <hip/hip_runtime.h>

#define BB 16
#define TT 4096
#define DD 512
#define CH 32               // rows per chunk in fused kernel
#define NY (TT/CH)          // 128 chunks per batch row
#define NEG (-1.0e30f)

// workspace float offsets
#define OFF_Q     64                         // 3*BB*DD
#define OFF_QP    (OFF_Q + 3*BB*DD)          // 4*3*BB*DD  (e-split partials)
#define OFF_P0    (OFF_QP + 4*3*BB*DD)       // BB*TT      (level-0 dots for att)
#define OFF_M     (OFF_P0 + BB*TT)           // 3*BB*NY    (per-chunk local max)
#define OFF_S     (OFF_M + 3*BB*NY)          // 3*BB*NY    (per-chunk exp-sum)
#define OFF_SC    (OFF_S + 3*BB*NY)          // 3*BB*NY    (per-chunk scale)
#define OFF_PART  (OFF_SC + 3*BB*NY)         // 3*NY*BB*DD (pooled partials, 12.5MB)
#define OFF_POOL  (OFF_PART + 3*NY*BB*DD)    // 3*BB*DD

// ---------------- K1: global mask layout detection + per-batch lengths -------
// One block per batch row. Detection must be GLOBAL (a byte-layout row with
// len==T has no nonzero odd bytes), so every block scans the odd-byte set
// (16K positions, L2-resident after the first block touches it).
__global__ void __launch_bounds__(256) k_lengths(const unsigned char* mask, int* lengths) {
    __shared__ int sflag;
    __shared__ int sred[4];
    const int tid = threadIdx.x;
    const int b = blockIdx.x;
    if (tid == 0) sflag = 0;
    __syncthreads();
    int f = 0;
    for (int idx = tid * 4 + 1; idx < BB * TT; idx += 256 * 4)
        f |= (mask[idx] != 0);
    if (f) atomicOr(&sflag, 1);
    __syncthreads();
    const bool byte_layout = (sflag != 0);
    const int* m32 = (const int*)mask;
    int cnt = 0;
    if (byte_layout) {
        for (int t = tid; t < TT; t += 256) cnt += (mask[b * TT + t] != 0);
    } else {
        for (int t = tid; t < TT; t += 256) cnt += (m32[b * TT + t] != 0);
    }
    #pragma unroll
    for (int m = 32; m >= 1; m >>= 1) cnt += __shfl_xor(cnt, m, 64);
    if ((tid & 63) == 0) sred[tid >> 6] = cnt;
    __syncthreads();
    if (tid == 0)
        lengths[b] = TT - (sred[0] + sred[1] + sred[2] + sred[3]);
}

// ------- K2: qpart[(i,b,ec),d] = sum_{e in ec-range} s_prev[b,e]*Vw[i,e,d] ---
__global__ void __launch_bounds__(256) k_q(const float* __restrict__ s_prev,
                                           const float* __restrict__ Vw,
                                           float* __restrict__ qpart) {
    const int blk = blockIdx.x;           // ((i*BB+b)*4 + ec), 192 blocks
    const int ec = blk & 3;
    const int ib = blk >> 2;
    const int b = ib % BB;
    const int i = ib / BB;
    const int d0 = threadIdx.x;
    const float* sp = s_prev + b * DD + ec * 128;
    const float* W = Vw + (size_t)i * DD * DD + (size_t)(ec * 128) * DD;
    float a0 = 0.f, a1 = 0.f;
    for (int e = 0; e < 128; e++) {
        const float se = sp[e];
        a0 += se * W[e * DD + d0];
        a1 += se * W[e * DD + d0 + 256];
    }
    qpart[(size_t)blk * DD + d0] = a0;
    qpart[(size_t)blk * DD + d0 + 256] = a1;
}

__global__ void __launch_bounds__(256) k_q_reduce(const float* __restrict__ qpart,
                                                  float* __restrict__ q) {
    const int idx = blockIdx.x * 256 + threadIdx.x;  // ib*DD+d, 24576
    const int ib = idx / DD;
    const int d = idx % DD;
    float s = 0.f;
    #pragma unroll
    for (int ec = 0; ec < 4; ec++) s += qpart[(size_t)(ib * 4 + ec) * DD + d];
    q[idx] = s;
}

// ---- K3 fused: dots + local windowed softmax + weighted pooling, 1 enc pass -
// Block = (b, chunk y): rows [t0, t0+CH) plus 2 boundary rows.
__global__ void __launch_bounds__(256) k_fused(const float* __restrict__ enc,
                                               const float* __restrict__ q,
                                               const int* __restrict__ lengths,
                                               float* __restrict__ p0,
                                               float* __restrict__ mbuf,
                                               float* __restrict__ sbuf,
                                               float* __restrict__ part) {
    __shared__ float sp[CH + 2][3];   // per-row dots, 3 levels
    __shared__ float svs[3][CH];      // windowed scores
    __shared__ float su[3][CH];       // raw exp weights
    __shared__ float sm[3];           // local max
    const int b = blockIdx.x;
    const int y = blockIdx.y;
    const int t0 = y * CH;
    const int len = lengths[b];
    const int tid = threadIdx.x;
    if (t0 >= len) {                  // fully masked chunk (block-uniform)
        if (tid < 3) {
            mbuf[(size_t)(tid * BB + b) * NY + y] = NEG;
            sbuf[(size_t)(tid * BB + b) * NY + y] = 0.f;
        }
        return;                       // scale==0 downstream; part slice unused
    }
    const int wv = tid >> 6, lane = tid & 63;

    // --- phase A: dots p_i[t] = enc[t] . q_i[b] for rows t0..t0+CH+1 ---
    const float4* q40 = (const float4*)(q + (size_t)(0 * BB + b) * DD);
    const float4* q41 = (const float4*)(q + (size_t)(1 * BB + b) * DD);
    const float4* q42 = (const float4*)(q + (size_t)(2 * BB + b) * DD);
    const float4 qa0 = q40[lane], qb0 = q40[64 + lane];
    const float4 qa1 = q41[lane], qb1 = q41[64 + lane];
    const float4 qa2 = q42[lane], qb2 = q42[64 + lane];
    #pragma unroll
    for (int rr = 0; rr < CH / 4 + 1; rr++) {
        if (rr == CH / 4 && wv >= 2) break;            // extras: wave0->CH, wave1->CH+1
        const int r = (rr < CH / 4) ? (wv + rr * 4) : (CH + wv);
        const int t = t0 + r;
        float d0 = 0.f, d1 = 0.f, d2 = 0.f;
        if (t < len) {                                  // wave-uniform
            const float4* e4 = (const float4*)(enc + ((size_t)b * TT + t) * DD);
            const float4 x0 = e4[lane], x1 = e4[64 + lane];
            d0 = x0.x*qa0.x + x0.y*qa0.y + x0.z*qa0.z + x0.w*qa0.w
               + x1.x*qb0.x + x1.y*qb0.y + x1.z*qb0.z + x1.w*qb0.w;
            d1 = x0.x*qa1.x + x0.y*qa1.y + x0.z*qa1.z + x0.w*qa1.w
               + x1.x*qb1.x + x1.y*qb1.y + x1.z*qb1.z + x1.w*qb1.w;
            d2 = x0.x*qa2.x + x0.y*qa2.y + x0.z*qa2.z + x0.w*qa2.w
               + x1.x*qb2.x + x1.y*qb2.y + x1.z*qb2.z + x1.w*qb2.w;
            #pragma unroll
            for (int m = 32; m >= 1; m >>= 1) {
                d0 += __shfl_xor(d0, m, 64);
                d1 += __shfl_xor(d1, m, 64);
                d2 += __shfl_xor(d2, m, 64);
            }
        }
        if (lane == 0) {
            sp[r][0] = d0; sp[r][1] = d1; sp[r][2] = d2;
            if (rr < CH / 4 && t < len) p0[(size_t)b * TT + t] = d0;
        }
    }
    __syncthreads();

    // --- windowed scores ---
    if (tid < 3 * CH) {
        const int i = tid / CH, r = tid % CH;
        const int l = t0 + r;
        const bool valid = l < (len - i);              // l <= len-k
        float s = sp[r][i];
        if (i > 0) s += sp[r + 1][i];
        if (i > 1) s += sp[r + 2][i];
        svs[i][r] = valid ? s * (1.0f / (float)(i + 1)) : NEG;
    }
    __syncthreads();
    if (tid < 3) {
        float m = NEG;
        #pragma unroll
        for (int r = 0; r < CH; r++) m = fmaxf(m, svs[tid][r]);
        sm[tid] = m;
    }
    __syncthreads();
    if (tid < 3 * CH) {
        const int i = tid / CH, r = tid % CH;
        const bool valid = (t0 + r) < (len - i);
        su[i][r] = valid ? __expf(svs[i][r] - sm[i]) : 0.f;
    }
    __syncthreads();
    if (tid < 3) {
        float s = 0.f;
        #pragma unroll
        for (int r = 0; r < CH; r++) s += su[tid][r];
        mbuf[(size_t)(tid * BB + b) * NY + y] = sm[tid];
        sbuf[(size_t)(tid * BB + b) * NY + y] = s;
    }
    __syncthreads();

    // --- phase B: partial pooled = sum_l u_l * ngram_l (rolling 3-row window) -
    const int d = tid * 2;    // two float columns per thread
    const float* col = enc + (size_t)b * TT * DD + d;
    float2 va, vb2, vc;
    {
        const int t = t0;
        va  = (t     < TT) ? *(const float2*)(col + (size_t)t * DD)       : make_float2(0.f, 0.f);
        vb2 = (t + 1 < TT) ? *(const float2*)(col + (size_t)(t + 1) * DD) : make_float2(0.f, 0.f);
    }
    float2 a0 = {0, 0}, a1 = {0, 0}, a2 = {0, 0};
    #pragma unroll
    for (int r = 0; r < CH; r++) {
        const int t = t0 + r;
        vc = (t + 2 < TT) ? *(const float2*)(col + (size_t)(t + 2) * DD) : make_float2(0.f, 0.f);
        const float u0 = su[0][r], u1 = su[1][r], u2 = su[2][r];
        const float w1x = va.x + vb2.x, w1y = va.y + vb2.y;
        const float w2x = w1x + vc.x,   w2y = w1y + vc.y;
        a0.x += u0 * va.x;  a0.y += u0 * va.y;
        a1.x += u1 * w1x;   a1.y += u1 * w1y;
        a2.x += u2 * w2x;   a2.y += u2 * w2y;
        va = vb2; vb2 = vc;
    }
    a1.x *= 0.5f; a1.y *= 0.5f;
    a2.x *= (1.0f / 3.0f); a2.y *= (1.0f / 3.0f);
    float* pt = part + (size_t)y * BB * DD + (size_t)b * DD + d;
    *(float2*)(pt)                            = a0;
    *(float2*)(pt + (size_t)NY * BB * DD)     = a1;
    *(float2*)(pt + (size_t)2 * NY * BB * DD) = a2;
}

// ------- K4: per-(i,b) global max/total -> per-chunk scales; i==0 -> att -----
__global__ void __launch_bounds__(256) k_combine(const float* __restrict__ mbuf,
                                                 const float* __restrict__ sbuf,
                                                 const float* __restrict__ p0,
                                                 const int* __restrict__ lengths,
                                                 float* __restrict__ scale,
                                                 float* __restrict__ att) {
    __shared__ float sred[4];
    __shared__ float sbc;
    const int g = blockIdx.x;            // (i*BB+b), 48 blocks
    const int i = g / BB, b = g % BB;
    const int tid = threadIdx.x;
    const float ml = (tid < NY) ? mbuf[(size_t)g * NY + tid] : NEG;
    const float sl = (tid < NY) ? sbuf[(size_t)g * NY + tid] : 0.f;
    // block max of ml
    float v = ml;
    #pragma unroll
    for (int m = 32; m >= 1; m >>= 1) v = fmaxf(v, __shfl_xor(v, m, 64));
    if ((tid & 63) == 0) sred[tid >> 6] = v;
    __syncthreads();
    if (tid == 0) sbc = fmaxf(fmaxf(sred[0], sred[1]), fmaxf(sred[2], sred[3]));
    __syncthreads();
    const float gm = sbc;
    __syncthreads();
    // block sum of sl * exp(ml - gm)
    const float e = (tid < NY) ? __expf(ml - gm) : 0.f;
    v = sl * e;
    #pragma unroll
    for (int m = 32; m >= 1; m >>= 1) v += __shfl_xor(v, m, 64);
    if ((tid & 63) == 0) sred[tid >> 6] = v;
    __syncthreads();
    if (tid == 0) sbc = sred[0] + sred[1] + sred[2] + sred[3];
    __syncthreads();
    const float inv = 1.0f / sbc;
    if (tid < NY) scale[(size_t)g * NY + tid] = e * inv;
    // level-0 groups also finalize att[b,:]
    if (i == 0) {
        const int len = lengths[b];
        for (int t = tid; t < TT; t += 256)
            att[(size_t)b * TT + t] =
                (t < len) ? __expf(p0[(size_t)b * TT + t] - gm) * inv : 0.f;
    }
}

// ------- K5: pooled[(i,b),d] = sum_y part[i][y][b][d] * scale[(i,b),y] -------
__global__ void __launch_bounds__(256) k_reduce(const float* __restrict__ part,
                                                const float* __restrict__ scale,
                                                float* __restrict__ pooled) {
    const int idx = blockIdx.x * 256 + threadIdx.x;  // (i*BB+b)*DD + d
    const int ib = idx / DD;
    const int d = idx % DD;
    const int i = ib / BB, b = ib % BB;
    const float* sc = scale + (size_t)ib * NY;
    const float* base = part + (size_t)i * NY * BB * DD + (size_t)b * DD + d;
    float s = 0.f;
    #pragma unroll 8
    for (int y = 0; y < NY; y++) s += base[(size_t)y * BB * DD] * sc[y];
    pooled[idx] = s;
}

// -------- K6: ctx[b,e] = sum_i (pooled_i[b,:] . Ww[i,e,:]) + sum_i Wb[i,e] ---
__global__ void __launch_bounds__(256) k_ctx(const float* __restrict__ pooled,
                                             const float* __restrict__ Ww,
                                             const float* __restrict__ Wb,
                                             float* __restrict__ ctx) {
    const int wid = blockIdx.x * 4 + (threadIdx.x >> 6);   // b*512 + e
    const int lane = threadIdx.x & 63;
    const int b = wid >> 9;
    const int e = wid & 511;
    float acc = 0.f;
    #pragma unroll
    for (int i = 0; i < 3; i++) {
        const float4* pr = (const float4*)(pooled + (size_t)(i * BB + b) * DD);
        const float4* wr = (const float4*)(Ww + ((size_t)i * DD + e) * DD);
        const float4 p0 = pr[lane], p1 = pr[64 + lane];
        const float4 w0 = wr[lane], w1 = wr[64 + lane];
        acc += p0.x * w0.x + p0.y * w0.y + p0.z * w0.z + p0.w * w0.w
             + p1.x * w1.x + p1.y * w1.y + p1.z * w1.z + p1.w * w1.w;
    }
    #pragma unroll
    for (int m = 32; m >= 1; m >>= 1) acc += __shfl_xor(acc, m, 64);
    if (lane == 0)
        ctx[(size_t)b * DD + e] = acc + Wb[e] + Wb[DD + e] + Wb[2 * DD + e];
}

extern "C" void kernel_launch(void* const* d_in, const int* in_sizes, int n_in,
                              void* d_out, int out_size, void* d_ws, size_t ws_size,
                              hipStream_t stream) {
    const float* s_prev = (const float*)d_in[0];
    const float* enc    = (const float*)d_in[1];
    const void*  mask   = d_in[2];
    const float* Vw     = (const float*)d_in[3];
    // d_in[4] = Vb: dead — constant shift under softmax
    const float* Ww     = (const float*)d_in[5];
    const float* Wb     = (const float*)d_in[6];

    float* out = (float*)d_out;
    float* ctx = out;              // [B, D]
    float* att = out + BB * DD;    // [B, T]

    float* W       = (float*)d_ws;
    int*   lengths = (int*)d_ws;
    float* q       = W + OFF_Q;
    float* qpart   = W + OFF_QP;
    float* p0      = W + OFF_P0;
    float* mbuf    = W + OFF_M;
    float* sbuf    = W + OFF_S;
    float* scale   = W + OFF_SC;
    float* part    = W + OFF_PART;
    float* pooled  = W + OFF_POOL;

    k_lengths<<<BB, 256, 0, stream>>>((const unsigned char*)mask, lengths);
    k_q<<<192, 256, 0, stream>>>(s_prev, Vw, qpart);
    k_q_reduce<<<3 * BB * DD / 256, 256, 0, stream>>>(qpart, q);
    k_fused<<<dim3(BB, NY), 256, 0, stream>>>(enc, q, lengths, p0, mbuf, sbuf, part);
    k_combine<<<3 * BB, 256, 0, stream>>>(mbuf, sbuf, p0, lengths, scale, att);
    k_reduce<<<3 * BB * DD / 256, 256, 0, stream>>>(part, scale, pooled);
    k_ctx<<<BB * DD / 4, 256, 0, stream>>>(pooled, Ww, Wb, ctx);
}

// Round 5
// 271.105 us; speedup vs baseline: 1.0163x; 1.0163x over previous
//
#include <hip/hip_runtime.h>

#define BB 16
#define TT 4096
#define DD 512
#define CH 16               // rows per chunk in fused kernel (measured-best)
#define NY (TT/CH)          // 256 chunks per batch row
#define NEG (-1.0e30f)

// workspace float offsets
#define OFF_Q     64                         // 3*BB*DD
#define OFF_QP    (OFF_Q + 3*BB*DD)          // 4*3*BB*DD  (e-split partials)
#define OFF_P0    (OFF_QP + 4*3*BB*DD)       // BB*TT      (level-0 dots for att)
#define OFF_M     (OFF_P0 + BB*TT)           // 3*BB*NY    (per-chunk local max)
#define OFF_S     (OFF_M + 3*BB*NY)          // 3*BB*NY    (per-chunk exp-sum)
#define OFF_SC    (OFF_S + 3*BB*NY)          // 3*BB*NY    (per-chunk scale)
#define OFF_PART  (OFF_SC + 3*BB*NY)         // 3*NY*BB*DD (pooled partials, 25MB)
#define OFF_POOL  (OFF_PART + 3*NY*BB*DD)    // 3*BB*DD

// ---------------- K1: global mask layout detection + per-batch lengths -------
__global__ void __launch_bounds__(256) k_lengths(const unsigned char* mask, int* lengths) {
    __shared__ int sflag;
    __shared__ int sred[4];
    const int tid = threadIdx.x;
    const int b = blockIdx.x;
    if (tid == 0) sflag = 0;
    __syncthreads();
    int f = 0;
    for (int idx = tid * 4 + 1; idx < BB * TT; idx += 256 * 4)
        f |= (mask[idx] != 0);
    if (f) atomicOr(&sflag, 1);
    __syncthreads();
    const bool byte_layout = (sflag != 0);
    const int* m32 = (const int*)mask;
    int cnt = 0;
    if (byte_layout) {
        for (int t = tid; t < TT; t += 256) cnt += (mask[b * TT + t] != 0);
    } else {
        for (int t = tid; t < TT; t += 256) cnt += (m32[b * TT + t] != 0);
    }
    #pragma unroll
    for (int m = 32; m >= 1; m >>= 1) cnt += __shfl_xor(cnt, m, 64);
    if ((tid & 63) == 0) sred[tid >> 6] = cnt;
    __syncthreads();
    if (tid == 0)
        lengths[b] = TT - (sred[0] + sred[1] + sred[2] + sred[3]);
}

// ------- K2: qpart[(i,b,ec),d] = sum_{e in ec-range} s_prev[b,e]*Vw[i,e,d] ---
__global__ void __launch_bounds__(256) k_q(const float* __restrict__ s_prev,
                                           const float* __restrict__ Vw,
                                           float* __restrict__ qpart) {
    const int blk = blockIdx.x;           // ((i*BB+b)*4 + ec), 192 blocks
    const int ec = blk & 3;
    const int ib = blk >> 2;
    const int b = ib % BB;
    const int i = ib / BB;
    const int d0 = threadIdx.x;
    const float* sp = s_prev + b * DD + ec * 128;
    const float* W = Vw + (size_t)i * DD * DD + (size_t)(ec * 128) * DD;
    float a0 = 0.f, a1 = 0.f;
    for (int e = 0; e < 128; e++) {
        const float se = sp[e];
        a0 += se * W[e * DD + d0];
        a1 += se * W[e * DD + d0 + 256];
    }
    qpart[(size_t)blk * DD + d0] = a0;
    qpart[(size_t)blk * DD + d0 + 256] = a1;
}

__global__ void __launch_bounds__(256) k_q_reduce(const float* __restrict__ qpart,
                                                  float* __restrict__ q) {
    const int idx = blockIdx.x * 256 + threadIdx.x;  // ib*DD+d, 24576
    const int ib = idx / DD;
    const int d = idx % DD;
    float s = 0.f;
    #pragma unroll
    for (int ec = 0; ec < 4; ec++) s += qpart[(size_t)(ib * 4 + ec) * DD + d];
    q[idx] = s;
}

// ---- K3 fused: dots + local windowed softmax + weighted pooling, 1 enc pass -
// Block = (b, chunk y): rows [t0, t0+CH) plus 2 boundary rows.
// Phase A: 8 subgroups of 32 lanes, one row per subgroup per iter
// (5-stage reduce instead of 6 -> 2.4x fewer cross-lane DS ops per row).
__global__ void __launch_bounds__(256) k_fused(const float* __restrict__ enc,
                                               const float* __restrict__ q,
                                               const int* __restrict__ lengths,
                                               float* __restrict__ p0,
                                               float* __restrict__ mbuf,
                                               float* __restrict__ sbuf,
                                               float* __restrict__ part) {
    __shared__ float sp[CH + 2][3];   // per-row dots, 3 levels
    __shared__ float svs[3][CH];      // windowed scores
    __shared__ float su[3][CH];       // raw exp weights
    __shared__ float sm[3];           // local max
    const int b = blockIdx.x;
    const int y = blockIdx.y;
    const int t0 = y * CH;
    const int len = lengths[b];
    const int tid = threadIdx.x;
    if (t0 >= len) {                  // fully masked chunk (block-uniform)
        if (tid < 3) {
            mbuf[(size_t)(tid * BB + b) * NY + y] = NEG;
            sbuf[(size_t)(tid * BB + b) * NY + y] = 0.f;
        }
        return;                       // scale==0 downstream; part slice unused
    }
    const int grp = tid >> 5;         // subgroup 0..7
    const int sl = tid & 31;          // lane within subgroup

    // q fragments: lane sl covers float4 indices sl + 32*j, j=0..3
    const float4* q40 = (const float4*)(q + (size_t)(0 * BB + b) * DD);
    const float4* q41 = (const float4*)(q + (size_t)(1 * BB + b) * DD);
    const float4* q42 = (const float4*)(q + (size_t)(2 * BB + b) * DD);
    float4 qf0[4], qf1[4], qf2[4];
    #pragma unroll
    for (int j = 0; j < 4; j++) {
        qf0[j] = q40[sl + 32 * j];
        qf1[j] = q41[sl + 32 * j];
        qf2[j] = q42[sl + 32 * j];
    }

    // --- phase A: dots for rows t0 .. t0+CH+1 ---
    #pragma unroll
    for (int rr = 0; rr < 3; rr++) {
        if (rr == 2 && grp >= 2) break;           // extras: grp0->16, grp1->17 (wave-uniform)
        const int r = (rr < 2) ? (grp + 8 * rr) : (CH + grp);
        const int t = t0 + r;
        float d0 = 0.f, d1 = 0.f, d2 = 0.f;
        if (t < len) {                             // subgroup-uniform; skips masked tail
            const float4* e4 = (const float4*)(enc + ((size_t)b * TT + t) * DD);
            #pragma unroll
            for (int j = 0; j < 4; j++) {
                const float4 x = e4[sl + 32 * j];
                d0 += x.x * qf0[j].x + x.y * qf0[j].y + x.z * qf0[j].z + x.w * qf0[j].w;
                d1 += x.x * qf1[j].x + x.y * qf1[j].y + x.z * qf1[j].z + x.w * qf1[j].w;
                d2 += x.x * qf2[j].x + x.y * qf2[j].y + x.z * qf2[j].z + x.w * qf2[j].w;
            }
        }
        #pragma unroll
        for (int m = 16; m >= 1; m >>= 1) {
            d0 += __shfl_xor(d0, m, 32);
            d1 += __shfl_xor(d1, m, 32);
            d2 += __shfl_xor(d2, m, 32);
        }
        if (sl == 0) {
            sp[r][0] = d0; sp[r][1] = d1; sp[r][2] = d2;
            if (r < CH && t < len) p0[(size_t)b * TT + t] = d0;
        }
    }
    __syncthreads();

    // --- windowed scores ---
    if (tid < 3 * CH) {
        const int i = tid / CH, r = tid % CH;
        const int l = t0 + r;
        const bool valid = l < (len - i);          // l <= len-k
        float s = sp[r][i];
        if (i > 0) s += sp[r + 1][i];
        if (i > 1) s += sp[r + 2][i];
        svs[i][r] = valid ? s * (1.0f / (float)(i + 1)) : NEG;
    }
    __syncthreads();
    if (tid < 3) {
        float m = NEG;
        #pragma unroll
        for (int r = 0; r < CH; r++) m = fmaxf(m, svs[tid][r]);
        sm[tid] = m;
    }
    __syncthreads();
    if (tid < 3 * CH) {
        const int i = tid / CH, r = tid % CH;
        const bool valid = (t0 + r) < (len - i);
        su[i][r] = valid ? __expf(svs[i][r] - sm[i]) : 0.f;
    }
    __syncthreads();
    if (tid < 3) {
        float s = 0.f;
        #pragma unroll
        for (int r = 0; r < CH; r++) s += su[tid][r];
        mbuf[(size_t)(tid * BB + b) * NY + y] = sm[tid];
        sbuf[(size_t)(tid * BB + b) * NY + y] = s;
    }
    __syncthreads();

    // --- phase B: partial pooled = sum_l u_l * ngram_l (rolling 3-row window) -
    const int d = tid * 2;    // two float columns per thread
    const float* col = enc + (size_t)b * TT * DD + d;
    float2 va, vb2, vc;
    {
        const int t = t0;
        va  = (t     < TT) ? *(const float2*)(col + (size_t)t * DD)       : make_float2(0.f, 0.f);
        vb2 = (t + 1 < TT) ? *(const float2*)(col + (size_t)(t + 1) * DD) : make_float2(0.f, 0.f);
    }
    float2 a0 = {0, 0}, a1 = {0, 0}, a2 = {0, 0};
    #pragma unroll
    for (int r = 0; r < CH; r++) {
        const int t = t0 + r;
        vc = (t + 2 < TT) ? *(const float2*)(col + (size_t)(t + 2) * DD) : make_float2(0.f, 0.f);
        const float u0 = su[0][r], u1 = su[1][r], u2 = su[2][r];
        const float w1x = va.x + vb2.x, w1y = va.y + vb2.y;
        const float w2x = w1x + vc.x,   w2y = w1y + vc.y;
        a0.x += u0 * va.x;  a0.y += u0 * va.y;
        a1.x += u1 * w1x;   a1.y += u1 * w1y;
        a2.x += u2 * w2x;   a2.y += u2 * w2y;
        va = vb2; vb2 = vc;
    }
    a1.x *= 0.5f; a1.y *= 0.5f;
    a2.x *= (1.0f / 3.0f); a2.y *= (1.0f / 3.0f);
    float* pt = part + (size_t)y * BB * DD + (size_t)b * DD + d;
    *(float2*)(pt)                            = a0;
    *(float2*)(pt + (size_t)NY * BB * DD)     = a1;
    *(float2*)(pt + (size_t)2 * NY * BB * DD) = a2;
}

// ------- K4: per-(i,b) global max/total -> per-chunk scales; i==0 -> att -----
__global__ void __launch_bounds__(256) k_combine(const float* __restrict__ mbuf,
                                                 const float* __restrict__ sbuf,
                                                 const float* __restrict__ p0,
                                                 const int* __restrict__ lengths,
                                                 float* __restrict__ scale,
                                                 float* __restrict__ att) {
    __shared__ float sred[4];
    __shared__ float sbc;
    const int g = blockIdx.x;            // (i*BB+b), 48 blocks
    const int i = g / BB, b = g % BB;
    const int tid = threadIdx.x;
    const float ml = mbuf[(size_t)g * NY + tid];
    const float sl = sbuf[(size_t)g * NY + tid];
    // block max of ml
    float v = ml;
    #pragma unroll
    for (int m = 32; m >= 1; m >>= 1) v = fmaxf(v, __shfl_xor(v, m, 64));
    if ((tid & 63) == 0) sred[tid >> 6] = v;
    __syncthreads();
    if (tid == 0) sbc = fmaxf(fmaxf(sred[0], sred[1]), fmaxf(sred[2], sred[3]));
    __syncthreads();
    const float gm = sbc;
    __syncthreads();
    // block sum of sl * exp(ml - gm)
    const float e = __expf(ml - gm);
    v = sl * e;
    #pragma unroll
    for (int m = 32; m >= 1; m >>= 1) v += __shfl_xor(v, m, 64);
    if ((tid & 63) == 0) sred[tid >> 6] = v;
    __syncthreads();
    if (tid == 0) sbc = sred[0] + sred[1] + sred[2] + sred[3];
    __syncthreads();
    const float inv = 1.0f / sbc;
    scale[(size_t)g * NY + tid] = e * inv;
    // level-0 groups also finalize att[b,:]
    if (i == 0) {
        const int len = lengths[b];
        for (int t = tid; t < TT; t += 256)
            att[(size_t)b * TT + t] =
                (t < len) ? __expf(p0[(size_t)b * TT + t] - gm) * inv : 0.f;
    }
}

// ------- K5: pooled[(i,b),d] = sum_y part[i][y][b][d] * scale[(i,b),y] -------
__global__ void __launch_bounds__(256) k_reduce(const float* __restrict__ part,
                                                const float* __restrict__ scale,
                                                float* __restrict__ pooled) {
    const int idx = blockIdx.x * 256 + threadIdx.x;  // (i*BB+b)*DD + d
    const int ib = idx / DD;
    const int d = idx % DD;
    const int i = ib / BB, b = ib % BB;
    const float* sc = scale + (size_t)ib * NY;
    const float* base = part + (size_t)i * NY * BB * DD + (size_t)b * DD + d;
    float s = 0.f;
    #pragma unroll 8
    for (int y = 0; y < NY; y++) s += base[(size_t)y * BB * DD] * sc[y];
    pooled[idx] = s;
}

// -------- K6: ctx[b,e] = sum_i (pooled_i[b,:] . Ww[i,e,:]) + sum_i Wb[i,e] ---
__global__ void __launch_bounds__(256) k_ctx(const float* __restrict__ pooled,
                                             const float* __restrict__ Ww,
                                             const float* __restrict__ Wb,
                                             float* __restrict__ ctx) {
    const int wid = blockIdx.x * 4 + (threadIdx.x >> 6);   // b*512 + e
    const int lane = threadIdx.x & 63;
    const int b = wid >> 9;
    const int e = wid & 511;
    float acc = 0.f;
    #pragma unroll
    for (int i = 0; i < 3; i++) {
        const float4* pr = (const float4*)(pooled + (size_t)(i * BB + b) * DD);
        const float4* wr = (const float4*)(Ww + ((size_t)i * DD + e) * DD);
        const float4 p0 = pr[lane], p1 = pr[64 + lane];
        const float4 w0 = wr[lane], w1 = wr[64 + lane];
        acc += p0.x * w0.x + p0.y * w0.y + p0.z * w0.z + p0.w * w0.w
             + p1.x * w1.x + p1.y * w1.y + p1.z * w1.z + p1.w * w1.w;
    }
    #pragma unroll
    for (int m = 32; m >= 1; m >>= 1) acc += __shfl_xor(acc, m, 64);
    if (lane == 0)
        ctx[(size_t)b * DD + e] = acc + Wb[e] + Wb[DD + e] + Wb[2 * DD + e];
}

extern "C" void kernel_launch(void* const* d_in, const int* in_sizes, int n_in,
                              void* d_out, int out_size, void* d_ws, size_t ws_size,
                              hipStream_t stream) {
    const float* s_prev = (const float*)d_in[0];
    const float* enc    = (const float*)d_in[1];
    const void*  mask   = d_in[2];
    const float* Vw     = (const float*)d_in[3];
    // d_in[4] = Vb: dead — constant shift under softmax
    const float* Ww     = (const float*)d_in[5];
    const float* Wb     = (const float*)d_in[6];

    float* out = (float*)d_out;
    float* ctx = out;              // [B, D]
    float* att = out + BB * DD;    // [B, T]

    float* W       = (float*)d_ws;
    int*   lengths = (int*)d_ws;
    float* q       = W + OFF_Q;
    float* qpart   = W + OFF_QP;
    float* p0      = W + OFF_P0;
    float* mbuf    = W + OFF_M;
    float* sbuf    = W + OFF_S;
    float* scale   = W + OFF_SC;
    float* part    = W + OFF_PART;
    float* pooled  = W + OFF_POOL;

    k_lengths<<<BB, 256, 0, stream>>>((const unsigned char*)mask, lengths);
    k_q<<<192, 256, 0, stream>>>(s_prev, Vw, qpart);
    k_q_reduce<<<3 * BB * DD / 256, 256, 0, stream>>>(qpart, q);
    k_fused<<<dim3(BB, NY), 256, 0, stream>>>(enc, q, lengths, p0, mbuf, sbuf, part);
    k_combine<<<3 * BB, 256, 0, stream>>>(mbuf, sbuf, p0, lengths, scale, att);
    k_reduce<<<3 * BB * DD / 256, 256, 0, stream>>>(part, scale, pooled);
    k_ctx<<<BB * DD / 4, 256, 0, stream>>>(pooled, Ww, Wb, ctx);
}